// Round 2
// baseline (489.671 us; speedup 1.0000x reference)
//
#include <hip/hip_runtime.h>

// HyperConnections: b=4, S=4, I=1, L=2048, D=2048. ALL tensors float32.
//
// Algebra: out[s,d] = sum_{s'} ( alpha[s'][s+1] + beta[s]*alpha[s'][0] ) * x[s',d]
//   alpha[s][t] = tanh( rms_s * sum_d x[s,d]*w[d]*A[d,t] ) * a_scale + static_alpha[s,t]
//   beta[s]     = tanh( rms_s * sum_d x[s,d]*w[d]*Bfn[d] ) * b_scale + static_beta[s]
//   rms_s = rsqrt(mean_d(x^2) + f32_eps)   -- rms factors out of the dots;
//   norm_weight w folds into the projection matrices (prep_kernel, into d_ws).

#define DD 2048
#define NS 4
#define NT 5

// Fold norm_weight into alpha/beta projections, transposed for coalesced reads.
__global__ void prep_kernel(const float* __restrict__ w,
                            const float* __restrict__ A,    // (D, 5) row-major
                            const float* __restrict__ Bfn,  // (D, 1)
                            float* __restrict__ WA,         // (5, D)
                            float* __restrict__ WB) {       // (D)
    int d = blockIdx.x * blockDim.x + threadIdx.x;
    if (d >= DD) return;
    float wf = w[d];
#pragma unroll
    for (int t = 0; t < NT; ++t)
        WA[t * DD + d] = wf * A[d * NT + t];
    WB[d] = wf * Bfn[d];
}

#define DOT4(ACC, V) do { \
    ACC = fmaf(xv.x, (V).x, ACC); \
    ACC = fmaf(xv.y, (V).y, ACC); \
    ACC = fmaf(xv.z, (V).z, ACC); \
    ACC = fmaf(xv.w, (V).w, ACC); \
} while (0)

#define ACC4(O, V, C) do { \
    O.x = fmaf((C), (V).x, O.x); \
    O.y = fmaf((C), (V).y, O.y); \
    O.z = fmaf((C), (V).z, O.z); \
    O.w = fmaf((C), (V).w, O.w); \
} while (0)

__global__ __launch_bounds__(256) void hyper_kernel(
    const float* __restrict__ X,    // residuals (16, 2048, 2048)
    const float* __restrict__ WA,   // (5, D)  w folded in
    const float* __restrict__ WB,   // (D)     w folded in
    const float* __restrict__ sA,   // static_alpha (4,5)
    const float* __restrict__ sB,   // static_beta  (4,1)
    const float* __restrict__ aS,   // dynamic_alpha_scale (1)
    const float* __restrict__ bS,   // dynamic_beta_scale  (1)
    float* __restrict__ out)
{
    __shared__ __align__(16) float xs[NS][DD];   // 32 KiB: the 4 rows of this group
    __shared__ float shA[NS][NT];                // alphas exchanged across waves

    const int g  = blockIdx.x;               // group = (bb, l)
    const int bb = g >> 11;
    const int l  = g & 2047;
    const int wv = threadIdx.x >> 6;         // wave = row s (4 waves, 4 rows)
    const int ln = threadIdx.x & 63;

    // residuals[(bb*4+s), l, :] is both input row and output row for s=wv
    const size_t rowOff = (((size_t)(bb * NS + wv)) * 2048 + (size_t)l) * (size_t)DD;

    float a0 = 0.f, a1 = 0.f, a2 = 0.f, a3 = 0.f, a4 = 0.f, ab = 0.f, ss = 0.f;

    // ---- Pass 1: load own row (16B/lane), stage to LDS, 7 fused dot products
#pragma unroll
    for (int it = 0; it < 8; ++it) {
        const int d0 = it * 256 + ln * 4;
        const float4 xv = *(const float4*)(X + rowOff + d0);
        *(float4*)&xs[wv][d0] = xv;
        ss = fmaf(xv.x, xv.x, ss);
        ss = fmaf(xv.y, xv.y, ss);
        ss = fmaf(xv.z, xv.z, ss);
        ss = fmaf(xv.w, xv.w, ss);

        const float4 w0 = *(const float4*)(WA + 0 * DD + d0);
        const float4 w1 = *(const float4*)(WA + 1 * DD + d0);
        const float4 w2 = *(const float4*)(WA + 2 * DD + d0);
        const float4 w3 = *(const float4*)(WA + 3 * DD + d0);
        const float4 w4 = *(const float4*)(WA + 4 * DD + d0);
        const float4 wb = *(const float4*)(WB + d0);
        DOT4(a0, w0); DOT4(a1, w1); DOT4(a2, w2);
        DOT4(a3, w3); DOT4(a4, w4); DOT4(ab, wb);
    }

    // ---- Wave butterfly reduction (all 64 lanes end with full sums)
#pragma unroll
    for (int m = 1; m < 64; m <<= 1) {
        a0 += __shfl_xor(a0, m);
        a1 += __shfl_xor(a1, m);
        a2 += __shfl_xor(a2, m);
        a3 += __shfl_xor(a3, m);
        a4 += __shfl_xor(a4, m);
        ab += __shfl_xor(ab, m);
        ss += __shfl_xor(ss, m);
    }

    // ---- Per-row scalars: rms, alpha[0..4], beta
    const float rms = rsqrtf(ss * (1.0f / 2048.0f) + 1.1920929e-07f); // f32 eps
    const float asc = aS[0];
    const float bsc = bS[0];
    const float be  = tanhf(rms * ab) * bsc + sB[wv];
    if (ln == 0) {
        shA[wv][0] = tanhf(rms * a0) * asc + sA[wv * NT + 0];
        shA[wv][1] = tanhf(rms * a1) * asc + sA[wv * NT + 1];
        shA[wv][2] = tanhf(rms * a2) * asc + sA[wv * NT + 2];
        shA[wv][3] = tanhf(rms * a3) * asc + sA[wv * NT + 3];
        shA[wv][4] = tanhf(rms * a4) * asc + sA[wv * NT + 4];
    }
    __syncthreads();

    // coeff[s'] = alpha[s'][wv+1] + beta[wv] * alpha[s'][0]
    const float c0 = shA[0][wv + 1] + be * shA[0][0];
    const float c1 = shA[1][wv + 1] + be * shA[1][0];
    const float c2 = shA[2][wv + 1] + be * shA[2][0];
    const float c3 = shA[3][wv + 1] + be * shA[3][0];

    // ---- Pass 2: 4x4 row mix from LDS, 16B stores
#pragma unroll
    for (int it = 0; it < 8; ++it) {
        const int d0 = it * 256 + ln * 4;
        const float4 v0 = *(const float4*)&xs[0][d0];
        const float4 v1 = *(const float4*)&xs[1][d0];
        const float4 v2 = *(const float4*)&xs[2][d0];
        const float4 v3 = *(const float4*)&xs[3][d0];
        float4 o = make_float4(0.f, 0.f, 0.f, 0.f);
        ACC4(o, v0, c0); ACC4(o, v1, c1); ACC4(o, v2, c2); ACC4(o, v3, c3);
        *(float4*)(out + rowOff + d0) = o;
    }
}

extern "C" void kernel_launch(void* const* d_in, const int* in_sizes, int n_in,
                              void* d_out, int out_size, void* d_ws, size_t ws_size,
                              hipStream_t stream) {
    const float* X   = (const float*)d_in[0]; // residuals (16,2048,2048)
    const float* w   = (const float*)d_in[1]; // norm_weight (2048)
    const float* sA  = (const float*)d_in[2]; // static_alpha (4,5)
    const float* sB  = (const float*)d_in[3]; // static_beta (4,1)
    const float* Afn = (const float*)d_in[4]; // dynamic_alpha_fn (2048,5)
    const float* aSc = (const float*)d_in[5]; // dynamic_alpha_scale (1)
    const float* Bfn = (const float*)d_in[6]; // dynamic_beta_fn (2048,1)
    const float* bSc = (const float*)d_in[7]; // dynamic_beta_scale (1)
    float* out = (float*)d_out;

    float* WA = (float*)d_ws;      // 5*2048 f32 = 40 KiB
    float* WB = WA + 5 * 2048;     // 2048 f32   =  8 KiB

    prep_kernel<<<8, 256, 0, stream>>>(w, Afn, Bfn, WA, WB);
    hyper_kernel<<<4 * 2048, 256, 0, stream>>>(X, WA, WB, sA, sB, aSc, bSc, out);
}